// Round 5
// baseline (183.958 us; speedup 1.0000x reference)
//
#include <hip/hip_runtime.h>

#define THREADS 256

typedef __attribute__((ext_vector_type(8))) short bf16x8;
typedef __attribute__((ext_vector_type(4))) float f32x4;

// fp32 -> bf16 with round-to-nearest-even (matches HW convert)
__device__ inline unsigned short f2bf(float f) {
    union { float f; unsigned int u; } v; v.f = f;
    unsigned int r = v.u + 0x7fffu + ((v.u >> 16) & 1u);
    return (unsigned short)(r >> 16);
}

// ---------------------------------------------------------------------------
// Kernel A: in-side contraction  x[N,4096] -> u3b[N,512] (bf16)
//   (EXACT round-0 proven version, ~21 us. FROZEN this round.)
// ---------------------------------------------------------------------------
__global__ __launch_bounds__(THREADS) void k_in_contract(
    const float* __restrict__ x,
    const float* __restrict__ f3, const float* __restrict__ f4,
    const float* __restrict__ f5,
    unsigned short* __restrict__ u3b, int N)
{
    const int n = blockIdx.x;
    const int t = threadIdx.x;

    __shared__ float fs[256];        // f3 [0..128) | f4 [128..256)
    __shared__ float u1s[256 * 9];   // [de][n6], pad 9 -> 2-way max
    __shared__ float u2s[128 * 9];   // [d*8+m][n6], pad 9

    if (t < 128) { fs[t] = f3[t]; fs[128 + t] = f4[t]; }

    float xv[16];
    {
        const float4* xr = (const float4*)(x + (size_t)n * 4096 + t * 16);
        float4 a0 = xr[0], a1 = xr[1], a2 = xr[2], a3 = xr[3];
        xv[0]=a0.x; xv[1]=a0.y; xv[2]=a0.z; xv[3]=a0.w;
        xv[4]=a1.x; xv[5]=a1.y; xv[6]=a1.z; xv[7]=a1.w;
        xv[8]=a2.x; xv[9]=a2.y; xv[10]=a2.z; xv[11]=a2.w;
        xv[12]=a3.x; xv[13]=a3.y; xv[14]=a3.z; xv[15]=a3.w;
    }

    float acc8[8];
    #pragma unroll
    for (int q = 0; q < 8; ++q) acc8[q] = 0.f;
    #pragma unroll
    for (int f = 0; f < 16; ++f) {
        const float xf = xv[f];
        #pragma unroll
        for (int n6 = 0; n6 < 8; ++n6)
            acc8[n6] = fmaf(xf, f5[f*8 + n6], acc8[n6]);
    }
    __syncthreads();
    #pragma unroll
    for (int n6 = 0; n6 < 8; ++n6) u1s[t*9 + n6] = acc8[n6];
    __syncthreads();

    {
        const int d = t >> 4, m = (t >> 1) & 7, h = t & 1;
        float fr[16];
        #pragma unroll
        for (int e = 0; e < 16; ++e) fr[e] = fs[128 + e*8 + m];
        float a4[4] = {0.f, 0.f, 0.f, 0.f};
        #pragma unroll
        for (int e = 0; e < 16; ++e) {
            const int base = (d*16 + e)*9 + h*4;
            #pragma unroll
            for (int q = 0; q < 4; ++q)
                a4[q] = fmaf(u1s[base + q], fr[e], a4[q]);
        }
        #pragma unroll
        for (int q = 0; q < 4; ++q) u2s[(d*8 + m)*9 + h*4 + q] = a4[q];
    }
    __syncthreads();

    {
        const int l = t >> 5, m = (t >> 2) & 7, h = t & 3;
        float fr[16];
        #pragma unroll
        for (int d = 0; d < 16; ++d) fr[d] = fs[d*8 + l];
        float a2[2] = {0.f, 0.f};
        #pragma unroll
        for (int d = 0; d < 16; ++d) {
            const int base = (d*8 + m)*9 + h*2;
            a2[0] = fmaf(u2s[base],     fr[d], a2[0]);
            a2[1] = fmaf(u2s[base + 1], fr[d], a2[1]);
        }
        unsigned int pk = (unsigned int)f2bf(a2[0]) |
                          ((unsigned int)f2bf(a2[1]) << 16);
        ((unsigned int*)u3b)[(size_t)n * 256 + t] = pk;
    }
}

// ---------------------------------------------------------------------------
// core fp32 [512,512] -> bf16. (FROZEN)
// ---------------------------------------------------------------------------
__global__ __launch_bounds__(THREADS) void k_convert_core(
    const float* __restrict__ core, unsigned short* __restrict__ coreb)
{
    const int i = blockIdx.x * THREADS + threadIdx.x;
    float4 c = ((const float4*)core)[i];
    ushort4 o;
    o.x = f2bf(c.x); o.y = f2bf(c.y); o.z = f2bf(c.z); o.w = f2bf(c.w);
    ((ushort4*)coreb)[i] = o;
}

// ---------------------------------------------------------------------------
// Kernel B (v3): MFMA GEMM, occupancy-first + B shared via L1.
//   v[n,p] = sum_q u3[n,q] * core[p,q]
//   Wave tile 16x16, K=512 unrolled (16 MFMA + 32 x 16B loads per wave).
//   Block = 4 waves: SAME p-tile (B-frag addresses identical across the 4
//   waves -> one L1 line set serves the block), consecutive 16-row m-tiles.
//   Grid (4096/64, 512/16) = (64,32) = 2048 blocks = 8 blocks/CU;
//   launch_bounds(256,8) -> <=64 VGPR (est ~30) -> 8 waves/SIMD, 4x the
//   occupancy of the old (32,16)-grid version which sat at 2 waves/SIMD.
//   A-frag: lane = row m0+(lane&15), k=(lane>>4)*8+j     [m89/m91]
//   C/D:    col = lane&15, row = (lane>>4)*4 + reg
// ---------------------------------------------------------------------------
__global__ __launch_bounds__(THREADS, 8) void k_core_gemm3(
    const unsigned short* __restrict__ u3b,
    const unsigned short* __restrict__ coreb,
    float* __restrict__ v, int N)
{
    const int t    = threadIdx.x;
    const int lane = t & 63;
    const int wave = t >> 6;
    const int m0 = blockIdx.x * 64 + wave * 16;
    const int p0 = blockIdx.y * 16;
    const int lr = lane & 15;
    const int lq = lane >> 4;

    const unsigned short* ap = u3b   + (size_t)(m0 + lr) * 512 + lq * 8;
    const unsigned short* bp = coreb + (size_t)(p0 + lr) * 512 + lq * 8;

    f32x4 acc = {0.f, 0.f, 0.f, 0.f};
    #pragma unroll
    for (int kt = 0; kt < 16; ++kt) {
        bf16x8 a = *(const bf16x8*)(ap + kt * 32);
        bf16x8 b = *(const bf16x8*)(bp + kt * 32);
        acc = __builtin_amdgcn_mfma_f32_16x16x32_bf16(a, b, acc, 0, 0, 0);
    }

    const int row = m0 + lq * 4;
    const int col = p0 + lr;
    #pragma unroll
    for (int r = 0; r < 4; ++r)
        v[(size_t)(row + r) * 512 + col] = acc[r];
}

// ---------------------------------------------------------------------------
// Kernel C (v3): out-side expansion, wave-per-row, ZERO block barriers.
//   y[n, a*256+b*16+c] = bias + sum_{i,j,k} v[n,i*64+j*8+k] f0[a,i] f1[b,j] f2[c,k]
//   All producer/consumer LDS sharing is wave-internal -> s_waitcnt
//   lgkmcnt(0) + sched_barrier(0) only (rule #18), no __syncthreads.
//   Differs from R2's regressed expand2 in ONE way: w1 is NOT hoisted into
//   a 64-register array (suspected spill under the 128-VGPR cap). Instead
//   the w2 stage streams w1 rows from LDS (b128, broadcast across the 4
//   lanes sharing 'a') into 4 unrolled per-b accumulators (compile-time
//   indexed only). Peak live ~70 VGPR.
//   Lane role: a = lane>>2 (0..15), s = lane&3 (0..3); lane handles
//   b in {s, 4+s, 8+s, 12+s}. Grid = N/4 blocks x 4 waves.
// ---------------------------------------------------------------------------
#define EXW 4   // rows (waves) per block

__global__ __launch_bounds__(THREADS, 4) void k_out_expand3(
    const float* __restrict__ v,
    const float* __restrict__ f0, const float* __restrict__ f1,
    const float* __restrict__ f2, const float* __restrict__ bias,
    float* __restrict__ y, int N)
{
    const int t    = threadIdx.x;
    const int wave = t >> 6;
    const int lane = t & 63;
    const int row  = blockIdx.x * EXW + wave;
    const int a = lane >> 2;     // 0..15
    const int s = lane & 3;      // 0..3

    __shared__ float vs[EXW][512];        // per-wave v row
    __shared__ float w1s[EXW][16 * 68];   // per-wave w1, [a][64] pad 68

    // ---- stage 0: v row -> LDS (2x float4 per lane, 32B contiguous) ----
    {
        const float4* vp = (const float4*)(v + (size_t)row * 512);
        float4 v0 = vp[lane * 2];
        float4 v1 = vp[lane * 2 + 1];
        float4* d = (float4*)&vs[wave][lane * 8];
        d[0] = v0; d[1] = v1;
    }
    asm volatile("s_waitcnt lgkmcnt(0)" ::: "memory");
    __builtin_amdgcn_sched_barrier(0);

    // ---- stage 1: w1[a][idx*4+q] = sum_i vs[i*64 + idx*4 + q] * f0[a,i] ----
    // idx in 0..15 (float offset idx*4); lane covers idx = {s,4+s,8+s,12+s}.
    {
        float fr[8];
        #pragma unroll
        for (int i = 0; i < 8; ++i) fr[i] = f0[a * 8 + i];   // L1-resident
        #pragma unroll
        for (int cmb = 0; cmb < 4; ++cmb) {
            const int idx = cmb * 4 + s;
            float ax = 0.f, ay = 0.f, az = 0.f, aw = 0.f;
            #pragma unroll
            for (int i = 0; i < 8; ++i) {
                float4 vv = *(const float4*)&vs[wave][i * 64 + idx * 4];
                const float fi = fr[i];
                ax = fmaf(vv.x, fi, ax); ay = fmaf(vv.y, fi, ay);
                az = fmaf(vv.z, fi, az); aw = fmaf(vv.w, fi, aw);
            }
            *(float4*)&w1s[wave][a * 68 + idx * 4] = make_float4(ax, ay, az, aw);
        }
    }
    asm volatile("s_waitcnt lgkmcnt(0)" ::: "memory");
    __builtin_amdgcn_sched_barrier(0);

    // ---- stage 2: stream w1 rows from LDS; 4 unrolled b-accumulators ----
    {
        // w2[bq][k]: b = bq*4 + s. All indices compile-time (fully unrolled).
        float w2_0[8] = {0.f,0.f,0.f,0.f,0.f,0.f,0.f,0.f};
        float w2_1[8] = {0.f,0.f,0.f,0.f,0.f,0.f,0.f,0.f};
        float w2_2[8] = {0.f,0.f,0.f,0.f,0.f,0.f,0.f,0.f};
        float w2_3[8] = {0.f,0.f,0.f,0.f,0.f,0.f,0.f,0.f};

        float fb0[8], fb1[8], fb2[8], fb3[8];
        #pragma unroll
        for (int j = 0; j < 8; ++j) {
            fb0[j] = f1[(0*4 + s) * 8 + j];
            fb1[j] = f1[(1*4 + s) * 8 + j];
            fb2[j] = f1[(2*4 + s) * 8 + j];
            fb3[j] = f1[(3*4 + s) * 8 + j];
        }

        #pragma unroll
        for (int j = 0; j < 8; ++j) {
            // one w1 row: 8 floats = 2 x b128, broadcast across lanes sharing a
            float4 wlo = *(const float4*)&w1s[wave][a * 68 + j * 8];
            float4 whi = *(const float4*)&w1s[wave][a * 68 + j * 8 + 4];
            const float wj[8] = {wlo.x, wlo.y, wlo.z, wlo.w,
                                 whi.x, whi.y, whi.z, whi.w};
            #pragma unroll
            for (int k = 0; k < 8; ++k) {
                w2_0[k] = fmaf(wj[k], fb0[j], w2_0[k]);
                w2_1[k] = fmaf(wj[k], fb1[j], w2_1[k]);
                w2_2[k] = fmaf(wj[k], fb2[j], w2_2[k]);
                w2_3[k] = fmaf(wj[k], fb3[j], w2_3[k]);
            }
        }

        // ---- y: for each of the lane's 4 b's, 16 output cols ----
        float* yrow = y + (size_t)row * 4096;
        #pragma unroll
        for (int bq = 0; bq < 4; ++bq) {
            const float* w2 = (bq == 0) ? w2_0 : (bq == 1) ? w2_1
                             : (bq == 2) ? w2_2 : w2_3;
            const int b = bq * 4 + s;
            const int ob = a * 256 + b * 16;
            const float4* bp4 = (const float4*)(bias + ob);
            float4* op = (float4*)(yrow + ob);
            #pragma unroll
            for (int cq = 0; cq < 4; ++cq) {
                float4 bb = bp4[cq];
                float r0 = bb.x, r1 = bb.y, r2 = bb.z, r3 = bb.w;
                #pragma unroll
                for (int k = 0; k < 8; ++k) {
                    // f2[c*8+k] lane-uniform -> s_loads
                    r0 = fmaf(w2[k], f2[(cq*4 + 0) * 8 + k], r0);
                    r1 = fmaf(w2[k], f2[(cq*4 + 1) * 8 + k], r1);
                    r2 = fmaf(w2[k], f2[(cq*4 + 2) * 8 + k], r2);
                    r3 = fmaf(w2[k], f2[(cq*4 + 3) * 8 + k], r3);
                }
                op[cq] = make_float4(r0, r1, r2, r3);
            }
        }
    }
}

// ---------------------------------------------------------------------------
extern "C" void kernel_launch(void* const* d_in, const int* in_sizes, int n_in,
                              void* d_out, int out_size, void* d_ws, size_t ws_size,
                              hipStream_t stream)
{
    const float* x    = (const float*)d_in[0];
    const float* core = (const float*)d_in[1];
    const float* f0   = (const float*)d_in[2];
    const float* f1   = (const float*)d_in[3];
    const float* f2   = (const float*)d_in[4];
    const float* f3   = (const float*)d_in[5];
    const float* f4   = (const float*)d_in[6];
    const float* f5   = (const float*)d_in[7];
    const float* bias = (const float*)d_in[8];
    float* y = (float*)d_out;

    const int N = in_sizes[0] / 4096;

    // workspace: u3b bf16 [N,512] (4MB) | coreb bf16 [512,512] (0.5MB)
    //          | v fp32 [N,512] (8MB)
    unsigned short* u3b   = (unsigned short*)d_ws;
    unsigned short* coreb = u3b + (size_t)N * 512;
    float*          v     = (float*)(coreb + 512 * 512);

    k_in_contract<<<N, THREADS, 0, stream>>>(x, f3, f4, f5, u3b, N);
    k_convert_core<<<256, THREADS, 0, stream>>>(core, coreb);
    dim3 gb(N / 64, 512 / 16);
    k_core_gemm3<<<gb, THREADS, 0, stream>>>(u3b, coreb, v, N);
    k_out_expand3<<<N / EXW, THREADS, 0, stream>>>(v, f0, f1, f2, bias, y, N);
}

// Round 6
// 171.078 us; speedup vs baseline: 1.0753x; 1.0753x over previous
//
#include <hip/hip_runtime.h>

#define THREADS 256

typedef __attribute__((ext_vector_type(8))) short bf16x8;
typedef __attribute__((ext_vector_type(4))) float f32x4;

// fp32 -> bf16 with round-to-nearest-even (matches HW convert)
__device__ inline unsigned short f2bf(float f) {
    union { float f; unsigned int u; } v; v.f = f;
    unsigned int r = v.u + 0x7fffu + ((v.u >> 16) & 1u);
    return (unsigned short)(r >> 16);
}

// ---------------------------------------------------------------------------
// Kernel A: in-side contraction  x[N,4096] -> u3b[N,512] (bf16)
//   (EXACT round-0 proven version. FROZEN.)
// ---------------------------------------------------------------------------
__global__ __launch_bounds__(THREADS) void k_in_contract(
    const float* __restrict__ x,
    const float* __restrict__ f3, const float* __restrict__ f4,
    const float* __restrict__ f5,
    unsigned short* __restrict__ u3b, int N)
{
    const int n = blockIdx.x;
    const int t = threadIdx.x;

    __shared__ float fs[256];        // f3 [0..128) | f4 [128..256)
    __shared__ float u1s[256 * 9];   // [de][n6], pad 9 -> 2-way max
    __shared__ float u2s[128 * 9];   // [d*8+m][n6], pad 9

    if (t < 128) { fs[t] = f3[t]; fs[128 + t] = f4[t]; }

    float xv[16];
    {
        const float4* xr = (const float4*)(x + (size_t)n * 4096 + t * 16);
        float4 a0 = xr[0], a1 = xr[1], a2 = xr[2], a3 = xr[3];
        xv[0]=a0.x; xv[1]=a0.y; xv[2]=a0.z; xv[3]=a0.w;
        xv[4]=a1.x; xv[5]=a1.y; xv[6]=a1.z; xv[7]=a1.w;
        xv[8]=a2.x; xv[9]=a2.y; xv[10]=a2.z; xv[11]=a2.w;
        xv[12]=a3.x; xv[13]=a3.y; xv[14]=a3.z; xv[15]=a3.w;
    }

    float acc8[8];
    #pragma unroll
    for (int q = 0; q < 8; ++q) acc8[q] = 0.f;
    #pragma unroll
    for (int f = 0; f < 16; ++f) {
        const float xf = xv[f];
        #pragma unroll
        for (int n6 = 0; n6 < 8; ++n6)
            acc8[n6] = fmaf(xf, f5[f*8 + n6], acc8[n6]);
    }
    __syncthreads();
    #pragma unroll
    for (int n6 = 0; n6 < 8; ++n6) u1s[t*9 + n6] = acc8[n6];
    __syncthreads();

    {
        const int d = t >> 4, m = (t >> 1) & 7, h = t & 1;
        float fr[16];
        #pragma unroll
        for (int e = 0; e < 16; ++e) fr[e] = fs[128 + e*8 + m];
        float a4[4] = {0.f, 0.f, 0.f, 0.f};
        #pragma unroll
        for (int e = 0; e < 16; ++e) {
            const int base = (d*16 + e)*9 + h*4;
            #pragma unroll
            for (int q = 0; q < 4; ++q)
                a4[q] = fmaf(u1s[base + q], fr[e], a4[q]);
        }
        #pragma unroll
        for (int q = 0; q < 4; ++q) u2s[(d*8 + m)*9 + h*4 + q] = a4[q];
    }
    __syncthreads();

    {
        const int l = t >> 5, m = (t >> 2) & 7, h = t & 3;
        float fr[16];
        #pragma unroll
        for (int d = 0; d < 16; ++d) fr[d] = fs[d*8 + l];
        float a2[2] = {0.f, 0.f};
        #pragma unroll
        for (int d = 0; d < 16; ++d) {
            const int base = (d*8 + m)*9 + h*2;
            a2[0] = fmaf(u2s[base],     fr[d], a2[0]);
            a2[1] = fmaf(u2s[base + 1], fr[d], a2[1]);
        }
        unsigned int pk = (unsigned int)f2bf(a2[0]) |
                          ((unsigned int)f2bf(a2[1]) << 16);
        ((unsigned int*)u3b)[(size_t)n * 256 + t] = pk;
    }
}

// ---------------------------------------------------------------------------
// core fp32 [512,512] -> bf16. (FROZEN)
// ---------------------------------------------------------------------------
__global__ __launch_bounds__(THREADS) void k_convert_core(
    const float* __restrict__ core, unsigned short* __restrict__ coreb)
{
    const int i = blockIdx.x * THREADS + threadIdx.x;
    float4 c = ((const float4*)core)[i];
    ushort4 o;
    o.x = f2bf(c.x); o.y = f2bf(c.y); o.z = f2bf(c.z); o.w = f2bf(c.w);
    ((ushort4*)coreb)[i] = o;
}

// ---------------------------------------------------------------------------
// Kernel B: MFMA GEMM (EXACT round-0 proven version. FROZEN — R5's gemm3
//   variant is unresolved; one experimental kernel per round.)
//   v[n,p] = sum_q u3[n,q] * core[p,q]
//   Wave tile 32x32 (2x2 of 16x16x32 bf16). Grid (32,16) = 512 blocks.
// ---------------------------------------------------------------------------
__global__ __launch_bounds__(THREADS) void k_core_gemm_mfma(
    const unsigned short* __restrict__ u3b,
    const unsigned short* __restrict__ coreb,
    float* __restrict__ v, int N)
{
    const int t    = threadIdx.x;
    const int lane = t & 63;
    const int wave = t >> 6;
    const int m0 = blockIdx.x * 128 + wave * 32;
    const int p0 = blockIdx.y * 32;
    const int lr = lane & 15;
    const int lq = lane >> 4;

    const unsigned short* aptr0 = u3b   + (size_t)(m0 + lr) * 512 + lq * 8;
    const unsigned short* aptr1 = aptr0 + 16 * 512;
    const unsigned short* bptr0 = coreb + (size_t)(p0 + lr) * 512 + lq * 8;
    const unsigned short* bptr1 = bptr0 + 16 * 512;

    f32x4 acc00 = {0.f,0.f,0.f,0.f}, acc01 = {0.f,0.f,0.f,0.f};
    f32x4 acc10 = {0.f,0.f,0.f,0.f}, acc11 = {0.f,0.f,0.f,0.f};

    #pragma unroll
    for (int k0 = 0; k0 < 512; k0 += 32) {
        bf16x8 a0 = *(const bf16x8*)(aptr0 + k0);
        bf16x8 a1 = *(const bf16x8*)(aptr1 + k0);
        bf16x8 b0 = *(const bf16x8*)(bptr0 + k0);
        bf16x8 b1 = *(const bf16x8*)(bptr1 + k0);
        acc00 = __builtin_amdgcn_mfma_f32_16x16x32_bf16(a0, b0, acc00, 0, 0, 0);
        acc01 = __builtin_amdgcn_mfma_f32_16x16x32_bf16(a0, b1, acc01, 0, 0, 0);
        acc10 = __builtin_amdgcn_mfma_f32_16x16x32_bf16(a1, b0, acc10, 0, 0, 0);
        acc11 = __builtin_amdgcn_mfma_f32_16x16x32_bf16(a1, b1, acc11, 0, 0, 0);
    }

    const int row = m0 + lq * 4;
    const int col = p0 + lr;
    #pragma unroll
    for (int r = 0; r < 4; ++r) {
        v[(size_t)(row + r) * 512 + col]           = acc00[r];
        v[(size_t)(row + r) * 512 + col + 16]      = acc01[r];
        v[(size_t)(row + 16 + r) * 512 + col]      = acc10[r];
        v[(size_t)(row + 16 + r) * 512 + col + 16] = acc11[r];
    }
}

// ---------------------------------------------------------------------------
// Kernel C (v4): wave-per-row expansion — R5's expand3 with the ONE codegen
//   pathology removed: R5 formed `const float* w2 = (bq==0)? w2_0 : ...`,
//   taking the ADDRESS of local arrays -> SROA defeated -> all four w2_*
//   accumulators demoted to scratch (R5 counters: WRITE_SIZE 105MB vs 64MB
//   of y, VGPR_Count 48, 47us). Fix: macro-expanded per-bq y-stage with the
//   NAMED array and literal indices only. Math identical (R5 passed).
// ---------------------------------------------------------------------------
#define EXW 4   // rows (waves) per block

__global__ __launch_bounds__(THREADS, 4) void k_out_expand4(
    const float* __restrict__ v,
    const float* __restrict__ f0, const float* __restrict__ f1,
    const float* __restrict__ f2, const float* __restrict__ bias,
    float* __restrict__ y, int N)
{
    const int t    = threadIdx.x;
    const int wave = t >> 6;
    const int lane = t & 63;
    const int row  = blockIdx.x * EXW + wave;
    const int a = lane >> 2;     // 0..15
    const int s = lane & 3;      // 0..3

    __shared__ float vs[EXW][512];        // per-wave v row
    __shared__ float w1s[EXW][16 * 68];   // per-wave w1, [a][64] pad 68

    // ---- stage 0: v row -> LDS (2x float4 per lane, 32B contiguous) ----
    {
        const float4* vp = (const float4*)(v + (size_t)row * 512);
        float4 v0 = vp[lane * 2];
        float4 v1 = vp[lane * 2 + 1];
        float4* d = (float4*)&vs[wave][lane * 8];
        d[0] = v0; d[1] = v1;
    }
    asm volatile("s_waitcnt lgkmcnt(0)" ::: "memory");
    __builtin_amdgcn_sched_barrier(0);

    // ---- stage 1: w1[a][idx*4+q] = sum_i vs[i*64 + idx*4 + q] * f0[a,i] ----
    {
        float fr[8];
        #pragma unroll
        for (int i = 0; i < 8; ++i) fr[i] = f0[a * 8 + i];
        #pragma unroll
        for (int cmb = 0; cmb < 4; ++cmb) {
            const int idx = cmb * 4 + s;
            float ax = 0.f, ay = 0.f, az = 0.f, aw = 0.f;
            #pragma unroll
            for (int i = 0; i < 8; ++i) {
                float4 vv = *(const float4*)&vs[wave][i * 64 + idx * 4];
                const float fi = fr[i];
                ax = fmaf(vv.x, fi, ax); ay = fmaf(vv.y, fi, ay);
                az = fmaf(vv.z, fi, az); aw = fmaf(vv.w, fi, aw);
            }
            *(float4*)&w1s[wave][a * 68 + idx * 4] = make_float4(ax, ay, az, aw);
        }
    }
    asm volatile("s_waitcnt lgkmcnt(0)" ::: "memory");
    __builtin_amdgcn_sched_barrier(0);

    // ---- stage 2: w2 accumulate (4 named arrays, static indices only) ----
    {
        float w2_0[8] = {0.f,0.f,0.f,0.f,0.f,0.f,0.f,0.f};
        float w2_1[8] = {0.f,0.f,0.f,0.f,0.f,0.f,0.f,0.f};
        float w2_2[8] = {0.f,0.f,0.f,0.f,0.f,0.f,0.f,0.f};
        float w2_3[8] = {0.f,0.f,0.f,0.f,0.f,0.f,0.f,0.f};

        float fb0[8], fb1[8], fb2[8], fb3[8];
        #pragma unroll
        for (int j = 0; j < 8; ++j) {
            fb0[j] = f1[(0*4 + s) * 8 + j];
            fb1[j] = f1[(1*4 + s) * 8 + j];
            fb2[j] = f1[(2*4 + s) * 8 + j];
            fb3[j] = f1[(3*4 + s) * 8 + j];
        }

        #pragma unroll
        for (int j = 0; j < 8; ++j) {
            float4 wlo = *(const float4*)&w1s[wave][a * 68 + j * 8];
            float4 whi = *(const float4*)&w1s[wave][a * 68 + j * 8 + 4];
            const float wj[8] = {wlo.x, wlo.y, wlo.z, wlo.w,
                                 whi.x, whi.y, whi.z, whi.w};
            #pragma unroll
            for (int k = 0; k < 8; ++k) {
                w2_0[k] = fmaf(wj[k], fb0[j], w2_0[k]);
                w2_1[k] = fmaf(wj[k], fb1[j], w2_1[k]);
                w2_2[k] = fmaf(wj[k], fb2[j], w2_2[k]);
                w2_3[k] = fmaf(wj[k], fb3[j], w2_3[k]);
            }
        }

        // ---- y-stage per bq: NAMED array, literal k — no pointer select ----
        float* yrow = y + (size_t)row * 4096;
#define BQ_BLOCK(BQ, W2)                                                    \
        {                                                                   \
            const int ob = a * 256 + (BQ * 4 + s) * 16;                     \
            const float4* bp4 = (const float4*)(bias + ob);                 \
            float4* op = (float4*)(yrow + ob);                              \
            _Pragma("unroll")                                               \
            for (int cq = 0; cq < 4; ++cq) {                                \
                float4 bb = bp4[cq];                                        \
                float r0 = bb.x, r1 = bb.y, r2 = bb.z, r3 = bb.w;           \
                _Pragma("unroll")                                           \
                for (int k = 0; k < 8; ++k) {                               \
                    r0 = fmaf(W2[k], f2[(cq*4 + 0) * 8 + k], r0);           \
                    r1 = fmaf(W2[k], f2[(cq*4 + 1) * 8 + k], r1);           \
                    r2 = fmaf(W2[k], f2[(cq*4 + 2) * 8 + k], r2);           \
                    r3 = fmaf(W2[k], f2[(cq*4 + 3) * 8 + k], r3);           \
                }                                                           \
                op[cq] = make_float4(r0, r1, r2, r3);                       \
            }                                                               \
        }
        BQ_BLOCK(0, w2_0)
        BQ_BLOCK(1, w2_1)
        BQ_BLOCK(2, w2_2)
        BQ_BLOCK(3, w2_3)
#undef BQ_BLOCK
    }
}

// ---------------------------------------------------------------------------
extern "C" void kernel_launch(void* const* d_in, const int* in_sizes, int n_in,
                              void* d_out, int out_size, void* d_ws, size_t ws_size,
                              hipStream_t stream)
{
    const float* x    = (const float*)d_in[0];
    const float* core = (const float*)d_in[1];
    const float* f0   = (const float*)d_in[2];
    const float* f1   = (const float*)d_in[3];
    const float* f2   = (const float*)d_in[4];
    const float* f3   = (const float*)d_in[5];
    const float* f4   = (const float*)d_in[6];
    const float* f5   = (const float*)d_in[7];
    const float* bias = (const float*)d_in[8];
    float* y = (float*)d_out;

    const int N = in_sizes[0] / 4096;

    // workspace: u3b bf16 [N,512] (4MB) | coreb bf16 [512,512] (0.5MB)
    //          | v fp32 [N,512] (8MB)
    unsigned short* u3b   = (unsigned short*)d_ws;
    unsigned short* coreb = u3b + (size_t)N * 512;
    float*          v     = (float*)(coreb + 512 * 512);

    k_in_contract<<<N, THREADS, 0, stream>>>(x, f3, f4, f5, u3b, N);
    k_convert_core<<<256, THREADS, 0, stream>>>(core, coreb);
    dim3 gb(N / 128, 512 / 32);
    k_core_gemm_mfma<<<gb, THREADS, 0, stream>>>(u3b, coreb, v, N);
    k_out_expand4<<<N / EXW, THREADS, 0, stream>>>(v, f0, f1, f2, bias, y, N);
}